// Round 1
// baseline (2407.395 us; speedup 1.0000x reference)
//
#include <hip/hip_runtime.h>
#include <cmath>

#define NNODES 30000
#define NFEATS 26
#define NEDGES 480000
#define TSNAPS 6
#define HIDDEN 7488
#define NOUT   26
#define CHEB_D 10     // degree of polynomial approx of e^z on [-2,0]

// ---------------------------------------------------------------- kernels

__global__ __launch_bounds__(256) void k_hist(const int* __restrict__ dst, int* __restrict__ cnt){
  int e = blockIdx.x*256 + threadIdx.x;
  if (e < NEDGES) atomicAdd(&cnt[dst[e]], 1);
}

__global__ __launch_bounds__(256) void k_invsqrt(const int* __restrict__ cnt, float* __restrict__ isq){
  int n = blockIdx.x*256 + threadIdx.x;
  if (n < NNODES){
    float d = (float)cnt[n];
    isq[n] = 1.0f / sqrtf(fmaxf(d, 1.0f));
  }
}

// exclusive scan of per-node counts -> row_ptr (single block, 1024 threads)
__global__ __launch_bounds__(1024) void k_scan(const int* __restrict__ cnt, int* __restrict__ rp){
  __shared__ int buf[1024];
  __shared__ int carry;
  if (threadIdx.x == 0){ carry = 0; rp[0] = 0; }
  __syncthreads();
  for (int base = 0; base < NNODES; base += 1024){
    int i = base + threadIdx.x;
    int v = (i < NNODES) ? cnt[i] : 0;
    buf[threadIdx.x] = v;
    __syncthreads();
    for (int off = 1; off < 1024; off <<= 1){
      int t = (threadIdx.x >= off) ? buf[threadIdx.x - off] : 0;
      __syncthreads();
      buf[threadIdx.x] += t;
      __syncthreads();
    }
    if (i < NNODES) rp[i+1] = carry + buf[threadIdx.x];
    __syncthreads();
    if (threadIdx.x == 0) carry += buf[1023];
    __syncthreads();
  }
}

__global__ __launch_bounds__(256) void k_fill(const int* __restrict__ src, const int* __restrict__ dst,
    const int* __restrict__ rp, int* __restrict__ fill, int* __restrict__ col,
    float* __restrict__ wcsr, const float* __restrict__ isq){
  int e = blockIdx.x*256 + threadIdx.x;
  if (e >= NEDGES) return;
  int d = dst[e], s = src[e];
  int pos = atomicAdd(&fill[d], 1);
  int i = rp[d] + pos;
  col[i]  = s;
  wcsr[i] = isq[s] * isq[d];
}

// Horner stage for q(L)h, L = P - I (P = sym-normalized adjacency):
// out[n,f] = A * ( sum_e w[e]*x[col[e],f] - x[n,f] ) + B * h[n,f]
// thread = (node, feat), 32 lanes per node (26 active) -> 104B coalesced row gathers
__global__ __launch_bounds__(256) void k_spmv_stage(const int* __restrict__ rp,
    const int* __restrict__ col, const float* __restrict__ wcsr,
    const float* __restrict__ x, const float* __restrict__ h,
    float* __restrict__ out, float A, float B){
  int tid = blockIdx.x*256 + threadIdx.x;
  int f = tid & 31;
  int n = tid >> 5;
  if (f >= NFEATS) return;
  int beg = rp[n], end = rp[n+1];
  float acc = 0.f;
  for (int e = beg; e < end; ++e){
    acc = fmaf(wcsr[e], x[(size_t)col[e]*NFEATS + f], acc);
  }
  size_t i = (size_t)n*NFEATS + f;
  out[i] = A * (acc - x[i]) + B * h[i];
}

// unweighted k-hop over all T snapshots: out[t,n,f] = sum_e x[t,col[e],f]
__global__ __launch_bounds__(256) void k_khop(const int* __restrict__ rp,
    const int* __restrict__ col, const float* __restrict__ x, float* __restrict__ out){
  int tid = blockIdx.x*256 + threadIdx.x;
  int f = tid & 31;
  int n = tid >> 5;
  if (f >= NFEATS) return;
  const float* xt = x   + (size_t)blockIdx.y*NNODES*NFEATS;
  float*       ot = out + (size_t)blockIdx.y*NNODES*NFEATS;
  int beg = rp[n], end = rp[n+1];
  float acc = 0.f;
  for (int e = beg; e < end; ++e){
    acc += xt[(size_t)col[e]*NFEATS + f];
  }
  ot[(size_t)n*NFEATS + f] = acc;
}

// power-sum moments: g[t,s,kk,m,f] += sum_n hk[t,n,f]^((m+1)(s+1))
// distinct powers: 1,2,3,4,6,8,9,12
#define MCHUNK 512
__global__ __launch_bounds__(256) void k_moments(const float* __restrict__ hk,
    float* __restrict__ g, int kk){
  int t   = blockIdx.y;
  int f   = threadIdx.x & 31;
  int sub = threadIdx.x >> 5;            // 0..7
  const float* ht = hk + (size_t)t*NNODES*NFEATS;
  int n0 = blockIdx.x*MCHUNK;
  int n1 = n0 + MCHUNK; if (n1 > NNODES) n1 = NNODES;
  float s1=0,s2=0,s3=0,s4=0,s6=0,s8=0,s9=0,s12=0;
  if (f < NFEATS){
    for (int n = n0 + sub; n < n1; n += 8){
      float h = ht[(size_t)n*NFEATS + f];
      float p2=h*h, p3=p2*h, p4=p2*p2, p6=p3*p3, p8=p4*p4, p9=p8*h, p12=p6*p6;
      s1+=h; s2+=p2; s3+=p3; s4+=p4; s6+=p6; s8+=p8; s9+=p9; s12+=p12;
    }
  }
  __shared__ float red[8][256];
  red[0][threadIdx.x]=s1; red[1][threadIdx.x]=s2; red[2][threadIdx.x]=s3; red[3][threadIdx.x]=s4;
  red[4][threadIdx.x]=s6; red[5][threadIdx.x]=s8; red[6][threadIdx.x]=s9; red[7][threadIdx.x]=s12;
  __syncthreads();
  if (sub == 0 && f < NFEATS){
    float tot[8];
    #pragma unroll
    for (int p=0;p<8;p++){
      float s=0;
      #pragma unroll
      for (int q=0;q<8;q++) s += red[p][f + 32*q];
      tot[p]=s;
    }
    const int map[3][4] = {{0,1,2,3},{1,3,4,5},{2,4,6,7}};
    #pragma unroll
    for (int s=0;s<3;s++)
      #pragma unroll
      for (int m=0;m<4;m++){
        int idx = ((((t*3+s)*4+kk)*4+m)*NFEATS) + f;
        atomicAdd(&g[idx], tot[map[s][m]]);
      }
  }
}

// one row per block, float4 streaming, LDS reduce
__global__ __launch_bounds__(256) void k_matvec(const float* __restrict__ W,
    const float* __restrict__ vin, const float* __restrict__ bias,
    float* __restrict__ vout, int cols, int do_relu){
  int row = blockIdx.x;
  const float* Wr = W + (size_t)row*cols;
  float acc = 0.f;
  for (int j = threadIdx.x*4; j < cols; j += 1024){
    float4 wv = *reinterpret_cast<const float4*>(Wr + j);
    float4 xv = *reinterpret_cast<const float4*>(vin + j);
    acc = fmaf(wv.x, xv.x, acc);
    acc = fmaf(wv.y, xv.y, acc);
    acc = fmaf(wv.z, xv.z, acc);
    acc = fmaf(wv.w, xv.w, acc);
  }
  __shared__ float red[256];
  red[threadIdx.x] = acc;
  __syncthreads();
  for (int off = 128; off > 0; off >>= 1){
    if (threadIdx.x < off) red[threadIdx.x] += red[threadIdx.x + off];
    __syncthreads();
  }
  if (threadIdx.x == 0){
    float r = red[0] + bias[row];
    vout[row] = do_relu ? fmaxf(r, 0.f) : r;
  }
}

// ---------------------------------------------------------------- host

// monomial coefficients (in z) of the degree-D Chebyshev expansion of e^z on [-2,0].
// x = z+1 in [-1,1]; e^z = e^{-1} * [ I0(1) + 2*sum_k Ik(1) Tk(x) ].
static void cheb_exp_coeffs(int D, double* a){
  double I[32];
  for (int k = 0; k <= D; ++k){
    double s = 0.0;
    for (int m = 0; m < 40; ++m){
      double term = 1.0;
      for (int q = 0; q < 2*m + k; ++q) term *= 0.5;
      for (int q = 2; q <= m;       ++q) term /= (double)q;
      for (int q = 2; q <= m + k;   ++q) term /= (double)q;
      s += term;
    }
    I[k] = s;
  }
  double Tm[32], Tc[32], Tn[32], acc[32];
  for (int j = 0; j < 32; ++j){ Tm[j]=0; Tc[j]=0; acc[j]=0; }
  Tm[0] = 1.0;                 // T0
  Tc[0] = 1.0; Tc[1] = 1.0;    // T1 = z + 1
  const double ei = exp(-1.0);
  acc[0] += ei * I[0];
  for (int j = 0; j <= 1; ++j) acc[j] += ei * 2.0 * I[1] * Tc[j];
  for (int k = 2; k <= D; ++k){
    for (int j = 0; j < 32; ++j) Tn[j] = 0;
    for (int j = 0; j < 31; ++j){ Tn[j] += 2.0*Tc[j]; Tn[j+1] += 2.0*Tc[j]; }
    for (int j = 0; j < 32; ++j) Tn[j] -= Tm[j];
    for (int j = 0; j <= k; ++j) acc[j] += ei * 2.0 * I[k] * Tn[j];
    for (int j = 0; j < 32; ++j){ Tm[j] = Tc[j]; Tc[j] = Tn[j]; }
  }
  for (int j = 0; j <= D; ++j) a[j] = acc[j];
}

extern "C" void kernel_launch(void* const* d_in, const int* in_sizes, int n_in,
                              void* d_out, int out_size, void* d_ws, size_t ws_size,
                              hipStream_t stream) {
  const float* x    = (const float*)d_in[0];
  const int*   ei   = (const int*)  d_in[1];
  const int*   esrc = ei;
  const int*   edst = ei + NEDGES;
  const float* W1   = (const float*)d_in[2];
  const float* b1   = (const float*)d_in[3];
  const float* W2   = (const float*)d_in[4];
  const float* b2   = (const float*)d_in[5];
  const float* Wc   = (const float*)d_in[6];
  const float* bc   = (const float*)d_in[7];
  float* out = (float*)d_out;

  // workspace layout (256B-aligned slices)
  char* wp = (char*)d_ws;
  auto alloc = [&](size_t bytes)->void*{
    void* p = wp; wp += ((bytes + 255) / 256) * 256; return p;
  };
  const size_t NF  = (size_t)NNODES * NFEATS;          // 780000
  const size_t TNF = (size_t)TSNAPS * NF;              // 4.68M
  int*   deg   = (int*)  alloc(NNODES * 4);
  int*   fillc = (int*)  alloc(NNODES * 4);
  float* g     = (float*)alloc(HIDDEN * 4);
  int*   rp    = (int*)  alloc((NNODES + 1) * 4);
  int*   col   = (int*)  alloc(NEDGES * 4);
  float* wcsr  = (float*)alloc(NEDGES * 4);
  float* isq   = (float*)alloc(NNODES * 4);
  float* u     = (float*)alloc(TNF * 4);
  float* ya    = (float*)alloc(NF * 4);
  float* yb    = (float*)alloc(NF * 4);
  float* hkA   = (float*)alloc(TNF * 4);
  float* hkB   = (float*)alloc(TNF * 4);
  float* v1    = (float*)alloc(HIDDEN * 4);
  float* v2    = (float*)alloc(HIDDEN * 4);

  hipMemsetAsync(deg,   0, NNODES * 4, stream);
  hipMemsetAsync(fillc, 0, NNODES * 4, stream);
  hipMemsetAsync(g,     0, HIDDEN * 4, stream);

  // CSR by dst + sym-normalized weights
  k_hist   <<<(NEDGES + 255)/256, 256, 0, stream>>>(edst, deg);
  k_invsqrt<<<(NNODES + 255)/256, 256, 0, stream>>>(deg, isq);
  k_scan   <<<1, 1024, 0, stream>>>(deg, rp);
  k_fill   <<<(NEDGES + 255)/256, 256, 0, stream>>>(esrc, edst, rp, fillc, col, wcsr, isq);

  // u[0] = x
  hipMemcpyAsync(u, x, NF * 4, hipMemcpyDeviceToDevice, stream);

  // heat diffusion: u[t+1] = q(L) u[t], q = deg-10 Chebyshev approx of e^z on [-2,0]
  // (matches RK4^10 to ~1e-4; x12 power amplification keeps us ~25x inside threshold)
  double a[32];
  cheb_exp_coeffs(CHEB_D, a);
  const int nb = (NNODES * 32) / 256;   // 3750 blocks, exact
  for (int t = 0; t < TSNAPS - 1; ++t){
    const float* h     = u + (size_t)t * NF;
    float*       unext = u + (size_t)(t + 1) * NF;
    const float* cur = h;
    float* pp[2] = { ya, yb };
    int pi = 0;
    for (int j = CHEB_D - 1; j >= 0; --j){
      float A = (j == CHEB_D - 1) ? (float)a[CHEB_D] : 1.0f;
      float B = (float)a[j];
      float* o = (j == 0) ? unext : pp[pi];
      k_spmv_stage<<<nb, 256, 0, stream>>>(rp, col, wcsr, cur, h, o, A, B);
      cur = o; pi ^= 1;
    }
  }

  // k-hop sums (unweighted, cumulative) + graph moments
  dim3 kg(nb, TSNAPS);
  dim3 mg((NNODES + MCHUNK - 1)/MCHUNK, TSNAPS);
  const float* hin = u;
  float* hop[2] = { hkA, hkB };
  for (int k = 0; k < 4; ++k){
    float* ho = hop[k & 1];
    k_khop   <<<kg, 256, 0, stream>>>(rp, col, hin, ho);
    k_moments<<<mg, 256, 0, stream>>>(ho, g, k);
    hin = ho;
  }

  // MLP head: v=g -> relu(W1 v+b1) -> relu(W2 .+b2) -> Wc .+bc
  k_matvec<<<HIDDEN, 256, 0, stream>>>(W1, g,  b1, v1,  HIDDEN, 1);
  k_matvec<<<HIDDEN, 256, 0, stream>>>(W2, v1, b2, v2,  HIDDEN, 1);
  k_matvec<<<NOUT,   256, 0, stream>>>(Wc, v2, bc, out, HIDDEN, 0);
}

// Round 2
// 1368.436 us; speedup vs baseline: 1.7592x; 1.7592x over previous
//
#include <hip/hip_runtime.h>
#include <cmath>

#define NNODES 30000
#define NFEATS 26
#define NEDGES 480000
#define TSNAPS 6
#define HIDDEN 7488
#define NOUT   26
#define CHEB_D 18          // Chebyshev basis degree for e^{t(P-I)}, t=1..5
#define SIGMA  1.25        // spectral domain margin: |lambda(P)| <= SIGMA
#define FP     32          // padded feature stride (128B rows)
#define NFP    ((size_t)NNODES * FP)   // 960000

// ---------------------------------------------------------------- kernels

__global__ __launch_bounds__(256) void k_hist(const int* __restrict__ dst, int* __restrict__ cnt){
  int e = blockIdx.x*256 + threadIdx.x;
  if (e < NEDGES) atomicAdd(&cnt[dst[e]], 1);
}

__global__ __launch_bounds__(256) void k_invsqrt(const int* __restrict__ cnt, float* __restrict__ isq){
  int n = blockIdx.x*256 + threadIdx.x;
  if (n < NNODES){
    float d = (float)cnt[n];
    isq[n] = 1.0f / sqrtf(fmaxf(d, 1.0f));
  }
}

// exclusive scan of per-node counts -> row_ptr; single block, shfl-based
__global__ __launch_bounds__(1024) void k_scan(const int* __restrict__ cnt, int* __restrict__ rp){
  __shared__ int wsum[16];
  int lane = threadIdx.x & 63, wid = threadIdx.x >> 6;
  if (threadIdx.x == 0) rp[0] = 0;
  int carry = 0;
  for (int base = 0; base < NNODES; base += 1024){
    int i = base + threadIdx.x;
    int v = (i < NNODES) ? cnt[i] : 0;
    int s = v;
    #pragma unroll
    for (int off = 1; off < 64; off <<= 1){
      int t = __shfl_up(s, off, 64);
      if (lane >= off) s += t;
    }
    if (lane == 63) wsum[wid] = s;
    __syncthreads();
    if (wid == 0){
      int ws = (lane < 16) ? wsum[lane] : 0;
      #pragma unroll
      for (int off = 1; off < 16; off <<= 1){
        int t = __shfl_up(ws, off, 64);
        if (lane >= off) ws += t;
      }
      if (lane < 16) wsum[lane] = ws;
    }
    __syncthreads();
    int wbase = (wid == 0) ? 0 : wsum[wid-1];
    if (i < NNODES) rp[i+1] = carry + wbase + s;
    carry += wsum[15];
    __syncthreads();
  }
}

__global__ __launch_bounds__(256) void k_fill(const int* __restrict__ src, const int* __restrict__ dst,
    const int* __restrict__ rp, int* __restrict__ fill, int* __restrict__ col,
    float* __restrict__ wcsr, const float* __restrict__ isq, float inv_sigma){
  int e = blockIdx.x*256 + threadIdx.x;
  if (e >= NEDGES) return;
  int d = dst[e], s = src[e];
  int pos = atomicAdd(&fill[d], 1);
  int i = rp[d] + pos;
  col[i]  = s;
  wcsr[i] = isq[s] * isq[d] * inv_sigma;   // weights pre-scaled by 1/sigma
}

// pad x (N,26) -> T0 (N,32), zero pad columns (pads stay 0 through the pipeline)
__global__ __launch_bounds__(256) void k_pad(const float* __restrict__ x, float* __restrict__ T0){
  int tid = blockIdx.x*256 + threadIdx.x;
  int f = tid & 31, n = tid >> 5;
  if (n >= NNODES) return;
  T0[(size_t)n*FP + f] = (f < NFEATS) ? x[(size_t)n*NFEATS + f] : 0.f;
}

// Chebyshev recurrence stage: Tnew = A * (P/sigma) Tcur - B * Tprev
// 16 lanes per node, float2 per lane -> each edge gather = one aligned 128B row
__global__ __launch_bounds__(256) void k_cheb(const int* __restrict__ rp,
    const int* __restrict__ col, const float* __restrict__ w,
    const float* __restrict__ Tcur, const float* __restrict__ Tprev,
    float* __restrict__ Tnew, float A, float B){
  int tid = blockIdx.x*256 + threadIdx.x;
  int lane = tid & 15;
  int n = tid >> 4;
  if (n >= NNODES) return;
  int beg = rp[n], end = rp[n+1];
  float2 acc = make_float2(0.f, 0.f);
  for (int e = beg; e < end; ++e){
    float wv = w[e];
    float2 v = *reinterpret_cast<const float2*>(Tcur + (size_t)col[e]*FP + lane*2);
    acc.x = fmaf(wv, v.x, acc.x);
    acc.y = fmaf(wv, v.y, acc.y);
  }
  size_t i = (size_t)n*FP + lane*2;
  float2 p = *reinterpret_cast<const float2*>(Tprev + i);
  float2 o = make_float2(A*acc.x - B*p.x, A*acc.y - B*p.y);
  *reinterpret_cast<float2*>(Tnew + i) = o;
}

// U[t] = sum_k c[t][k] T_k   (t=0..5; c[0][k]=delta_k0 so U[0]=x padded)
struct Coefs { float c[TSNAPS][CHEB_D + 1]; };
__global__ __launch_bounds__(256) void k_combine(const float* __restrict__ T,
    float* __restrict__ U, Coefs cf){
  size_t i = ((size_t)blockIdx.x*256 + threadIdx.x) * 4;
  if (i >= NFP) return;
  float4 acc[TSNAPS];
  #pragma unroll
  for (int t = 0; t < TSNAPS; ++t) acc[t] = make_float4(0,0,0,0);
  #pragma unroll
  for (int k = 0; k <= CHEB_D; ++k){
    float4 tv = *reinterpret_cast<const float4*>(T + (size_t)k*NFP + i);
    #pragma unroll
    for (int t = 0; t < TSNAPS; ++t){
      float c = cf.c[t][k];
      acc[t].x = fmaf(c, tv.x, acc[t].x);
      acc[t].y = fmaf(c, tv.y, acc[t].y);
      acc[t].z = fmaf(c, tv.z, acc[t].z);
      acc[t].w = fmaf(c, tv.w, acc[t].w);
    }
  }
  #pragma unroll
  for (int t = 0; t < TSNAPS; ++t)
    *reinterpret_cast<float4*>(U + (size_t)t*NFP + i) = acc[t];
}

// unweighted 1-hop neighbor sum for one snapshot (padded layout)
__global__ __launch_bounds__(256) void k_khop(const int* __restrict__ rp,
    const int* __restrict__ col, const float* __restrict__ xin, float* __restrict__ xout){
  int tid = blockIdx.x*256 + threadIdx.x;
  int lane = tid & 15;
  int n = tid >> 4;
  if (n >= NNODES) return;
  int beg = rp[n], end = rp[n+1];
  float2 acc = make_float2(0.f, 0.f);
  for (int e = beg; e < end; ++e){
    float2 v = *reinterpret_cast<const float2*>(xin + (size_t)col[e]*FP + lane*2);
    acc.x += v.x;
    acc.y += v.y;
  }
  *reinterpret_cast<float2*>(xout + (size_t)n*FP + lane*2) = acc;
}

// power-sum moments: g[t,s,kk,m,f] += sum_n hk[t,n,f]^((m+1)(s+1))
#define MCHUNK 512
__global__ __launch_bounds__(256) void k_moments(const float* __restrict__ hk,
    float* __restrict__ g, int kk){
  int t   = blockIdx.y;
  int f   = threadIdx.x & 31;
  int sub = threadIdx.x >> 5;            // 0..7
  const float* ht = hk + (size_t)t*NFP;
  int n0 = blockIdx.x*MCHUNK;
  int n1 = n0 + MCHUNK; if (n1 > NNODES) n1 = NNODES;
  float s1=0,s2=0,s3=0,s4=0,s6=0,s8=0,s9=0,s12=0;
  if (f < NFEATS){
    for (int n = n0 + sub; n < n1; n += 8){
      float h = ht[(size_t)n*FP + f];
      float p2=h*h, p3=p2*h, p4=p2*p2, p6=p3*p3, p8=p4*p4, p9=p8*h, p12=p6*p6;
      s1+=h; s2+=p2; s3+=p3; s4+=p4; s6+=p6; s8+=p8; s9+=p9; s12+=p12;
    }
  }
  __shared__ float red[8][256];
  red[0][threadIdx.x]=s1; red[1][threadIdx.x]=s2; red[2][threadIdx.x]=s3; red[3][threadIdx.x]=s4;
  red[4][threadIdx.x]=s6; red[5][threadIdx.x]=s8; red[6][threadIdx.x]=s9; red[7][threadIdx.x]=s12;
  __syncthreads();
  if (sub == 0 && f < NFEATS){
    float tot[8];
    #pragma unroll
    for (int p=0;p<8;p++){
      float s=0;
      #pragma unroll
      for (int q=0;q<8;q++) s += red[p][f + 32*q];
      tot[p]=s;
    }
    const int map[3][4] = {{0,1,2,3},{1,3,4,5},{2,4,6,7}};
    #pragma unroll
    for (int s=0;s<3;s++)
      #pragma unroll
      for (int m=0;m<4;m++){
        int idx = ((((t*3+s)*4+kk)*4+m)*NFEATS) + f;
        atomicAdd(&g[idx], tot[map[s][m]]);
      }
  }
}

// one row per block, float4 streaming, LDS reduce
__global__ __launch_bounds__(256) void k_matvec(const float* __restrict__ W,
    const float* __restrict__ vin, const float* __restrict__ bias,
    float* __restrict__ vout, int cols, int do_relu){
  int row = blockIdx.x;
  const float* Wr = W + (size_t)row*cols;
  float acc = 0.f;
  for (int j = threadIdx.x*4; j < cols; j += 1024){
    float4 wv = *reinterpret_cast<const float4*>(Wr + j);
    float4 xv = *reinterpret_cast<const float4*>(vin + j);
    acc = fmaf(wv.x, xv.x, acc);
    acc = fmaf(wv.y, xv.y, acc);
    acc = fmaf(wv.z, xv.z, acc);
    acc = fmaf(wv.w, xv.w, acc);
  }
  __shared__ float red[256];
  red[threadIdx.x] = acc;
  __syncthreads();
  for (int off = 128; off > 0; off >>= 1){
    if (threadIdx.x < off) red[threadIdx.x] += red[threadIdx.x + off];
    __syncthreads();
  }
  if (threadIdx.x == 0){
    float r = red[0] + bias[row];
    vout[row] = do_relu ? fmaxf(r, 0.f) : r;
  }
}

// ---------------------------------------------------------------- host

// modified Bessel I_k(a) by series, double precision
static double bessel_i(int k, double a){
  double half = 0.5 * a;
  double t = 1.0;
  for (int q = 1; q <= k; ++q) t *= half / (double)q;   // half^k / k!
  double sum = t;
  for (int m = 1; m < 80; ++m){
    t *= half * half / ((double)m * (double)(m + k));
    sum += t;
    if (t < sum * 1e-18) break;
  }
  return sum;
}

extern "C" void kernel_launch(void* const* d_in, const int* in_sizes, int n_in,
                              void* d_out, int out_size, void* d_ws, size_t ws_size,
                              hipStream_t stream) {
  const float* x    = (const float*)d_in[0];
  const int*   ei   = (const int*)  d_in[1];
  const int*   esrc = ei;
  const int*   edst = ei + NEDGES;
  const float* W1   = (const float*)d_in[2];
  const float* b1   = (const float*)d_in[3];
  const float* W2   = (const float*)d_in[4];
  const float* b2   = (const float*)d_in[5];
  const float* Wc   = (const float*)d_in[6];
  const float* bc   = (const float*)d_in[7];
  float* out = (float*)d_out;

  // workspace layout (256B-aligned slices)
  char* wp = (char*)d_ws;
  auto alloc = [&](size_t bytes)->void*{
    void* p = wp; wp += ((bytes + 255) / 256) * 256; return p;
  };
  int*   deg   = (int*)  alloc(NNODES * 4);
  int*   fillc = (int*)  alloc(NNODES * 4);
  float* g     = (float*)alloc(HIDDEN * 4);
  int*   rp    = (int*)  alloc((NNODES + 1) * 4);
  int*   col   = (int*)  alloc(NEDGES * 4);
  float* wcsr  = (float*)alloc(NEDGES * 4);
  float* isq   = (float*)alloc(NNODES * 4);
  float* Tbuf  = (float*)alloc((CHEB_D + 1) * NFP * 4);   // Chebyshev basis vectors
  float* U     = (float*)alloc(TSNAPS * NFP * 4);         // snapshots t=0..5
  float* hkA   = (float*)alloc(TSNAPS * NFP * 4);
  float* hkB   = (float*)alloc(TSNAPS * NFP * 4);
  float* v1    = (float*)alloc(HIDDEN * 4);
  float* v2    = (float*)alloc(HIDDEN * 4);

  hipMemsetAsync(deg,   0, NNODES * 4, stream);
  hipMemsetAsync(fillc, 0, NNODES * 4, stream);
  hipMemsetAsync(g,     0, HIDDEN * 4, stream);

  // CSR by dst + sym-normalized weights (pre-scaled by 1/SIGMA)
  k_hist   <<<(NEDGES + 255)/256, 256, 0, stream>>>(edst, deg);
  k_invsqrt<<<(NNODES + 255)/256, 256, 0, stream>>>(deg, isq);
  k_scan   <<<1, 1024, 0, stream>>>(deg, rp);
  k_fill   <<<(NEDGES + 255)/256, 256, 0, stream>>>(esrc, edst, rp, fillc, col, wcsr, isq,
                                                    (float)(1.0 / SIGMA));

  // T0 = x padded to stride 32 (pad columns zero)
  k_pad<<<(NNODES*32 + 255)/256, 256, 0, stream>>>(x, Tbuf);

  // Chebyshev basis: T_k = T_k(P/SIGMA) x via 3-term recurrence (one SpMV each)
  const int nbs = (NNODES*16 + 255)/256;   // 1875
  for (int k = 1; k <= CHEB_D; ++k){
    const float* Tc = Tbuf + (size_t)(k-1)*NFP;
    const float* Tp = Tbuf + (size_t)((k >= 2) ? (k-2) : 0)*NFP;
    float*       Tn = Tbuf + (size_t)k*NFP;
    k_cheb<<<nbs, 256, 0, stream>>>(rp, col, wcsr, Tc, Tp, Tn,
                                    (k == 1) ? 1.f : 2.f, (k == 1) ? 0.f : 1.f);
  }

  // u[t] = e^{-t} [ I0(t*SIGMA) + 2 sum_k Ik(t*SIGMA) T_k ] x
  Coefs cf{};
  cf.c[0][0] = 1.f;
  for (int t = 1; t < TSNAPS; ++t){
    double et = exp(-(double)t);
    for (int k = 0; k <= CHEB_D; ++k)
      cf.c[t][k] = (float)(et * (k ? 2.0 : 1.0) * bessel_i(k, (double)t * SIGMA));
  }
  k_combine<<<(int)((NFP/4 + 255)/256), 256, 0, stream>>>(Tbuf, U, cf);

  // k-hop sums (unweighted, cumulative) + graph moments; per-snapshot launches
  // keep each 3.84MB state resident in the per-XCD L2
  dim3 mg((NNODES + MCHUNK - 1)/MCHUNK, TSNAPS);
  const float* hin = U;
  float* hop[2] = { hkA, hkB };
  for (int k = 0; k < 4; ++k){
    float* ho = hop[k & 1];
    for (int t = 0; t < TSNAPS; ++t)
      k_khop<<<nbs, 256, 0, stream>>>(rp, col, hin + (size_t)t*NFP, ho + (size_t)t*NFP);
    k_moments<<<mg, 256, 0, stream>>>(ho, g, k);
    hin = ho;
  }

  // MLP head: v=g -> relu(W1 v+b1) -> relu(W2 .+b2) -> Wc .+bc
  k_matvec<<<HIDDEN, 256, 0, stream>>>(W1, g,  b1, v1,  HIDDEN, 1);
  k_matvec<<<HIDDEN, 256, 0, stream>>>(W2, v1, b2, v2,  HIDDEN, 1);
  k_matvec<<<NOUT,   256, 0, stream>>>(Wc, v2, bc, out, HIDDEN, 0);
}

// Round 7
// 1053.523 us; speedup vs baseline: 2.2851x; 1.2989x over previous
//
#include <hip/hip_runtime.h>
#include <cmath>

#define NNODES 30000
#define NFEATS 26
#define NEDGES 480000
#define TSNAPS 6
#define HIDDEN 7488
#define NOUT   26
#define CHEB_D 18          // Chebyshev basis degree for e^{t(P-I)}, t=1..5
#define SIGMA  1.25        // spectral domain margin: |lambda(P)| <= SIGMA
#define FP     32          // padded feature stride (128B rows)
#define NFP    ((size_t)NNODES * FP)   // 960000

typedef float vf4 __attribute__((ext_vector_type(4)));

// ---------------------------------------------------------------- kernels

__global__ __launch_bounds__(256) void k_hist(const int* __restrict__ dst, int* __restrict__ cnt){
  int e = blockIdx.x*256 + threadIdx.x;
  if (e < NEDGES) atomicAdd(&cnt[dst[e]], 1);
}

// exclusive scan of per-node counts -> row_ptr; single block, shfl-based
__global__ __launch_bounds__(1024) void k_scan(const int* __restrict__ cnt, int* __restrict__ rp){
  __shared__ int wsum[16];
  int lane = threadIdx.x & 63, wid = threadIdx.x >> 6;
  if (threadIdx.x == 0) rp[0] = 0;
  int carry = 0;
  for (int base = 0; base < NNODES; base += 1024){
    int i = base + threadIdx.x;
    int v = (i < NNODES) ? cnt[i] : 0;
    int s = v;
    #pragma unroll
    for (int off = 1; off < 64; off <<= 1){
      int t = __shfl_up(s, off, 64);
      if (lane >= off) s += t;
    }
    if (lane == 63) wsum[wid] = s;
    __syncthreads();
    if (wid == 0){
      int ws = (lane < 16) ? wsum[lane] : 0;
      #pragma unroll
      for (int off = 1; off < 16; off <<= 1){
        int t = __shfl_up(ws, off, 64);
        if (lane >= off) ws += t;
      }
      if (lane < 16) wsum[lane] = ws;
    }
    __syncthreads();
    int wbase = (wid == 0) ? 0 : wsum[wid-1];
    if (i < NNODES) rp[i+1] = carry + wbase + s;
    carry += wsum[15];
    __syncthreads();
  }
}

// CSR fill: col[] (for khop) and packed edge[]=(col, w) (for cheb), w inline from degrees
__global__ __launch_bounds__(256) void k_fill(const int* __restrict__ src, const int* __restrict__ dst,
    const int* __restrict__ rp, const int* __restrict__ cnt, int* __restrict__ fill,
    int* __restrict__ col, int2* __restrict__ edge, float inv_sigma){
  int e = blockIdx.x*256 + threadIdx.x;
  if (e >= NEDGES) return;
  int d = dst[e], s = src[e];
  int pos = atomicAdd(&fill[d], 1);
  int i = rp[d] + pos;
  float w = inv_sigma / sqrtf(fmaxf((float)cnt[s], 1.f) * fmaxf((float)cnt[d], 1.f));
  col[i]  = s;
  edge[i] = make_int2(s, __float_as_int(w));
}

// pad x (N,26) -> T0 (N,32), zero pad columns (pads stay 0 through the pipeline)
__global__ __launch_bounds__(256) void k_pad(const float* __restrict__ x, float* __restrict__ T0){
  int tid = blockIdx.x*256 + threadIdx.x;
  int f = tid & 31, n = tid >> 5;
  if (n >= NNODES) return;
  T0[(size_t)n*FP + f] = (f < NFEATS) ? x[(size_t)n*NFEATS + f] : 0.f;
}

// Chebyshev recurrence stage: Tnew = A * (P/sigma) Tcur - B * Tprev
// 8 lanes per node, float4 per lane; packed edge loads; 2-edge unroll for ILP
__global__ __launch_bounds__(256) void k_cheb(const int* __restrict__ rp,
    const int2* __restrict__ edge,
    const float* __restrict__ Tcur, const float* __restrict__ Tprev,
    float* __restrict__ Tnew, float A, float B){
  int tid = blockIdx.x*256 + threadIdx.x;
  int lane = tid & 7;
  int n = tid >> 3;
  if (n >= NNODES) return;
  int beg = rp[n], end = rp[n+1];
  float4 a0 = make_float4(0,0,0,0), a1 = make_float4(0,0,0,0);
  int e = beg;
  for (; e + 1 < end; e += 2){
    int2 e0 = edge[e], e1 = edge[e+1];
    float w0 = __int_as_float(e0.y), w1 = __int_as_float(e1.y);
    float4 v0 = *reinterpret_cast<const float4*>(Tcur + (size_t)e0.x*FP + lane*4);
    float4 v1 = *reinterpret_cast<const float4*>(Tcur + (size_t)e1.x*FP + lane*4);
    a0.x = fmaf(w0, v0.x, a0.x); a0.y = fmaf(w0, v0.y, a0.y);
    a0.z = fmaf(w0, v0.z, a0.z); a0.w = fmaf(w0, v0.w, a0.w);
    a1.x = fmaf(w1, v1.x, a1.x); a1.y = fmaf(w1, v1.y, a1.y);
    a1.z = fmaf(w1, v1.z, a1.z); a1.w = fmaf(w1, v1.w, a1.w);
  }
  if (e < end){
    int2 e0 = edge[e];
    float w0 = __int_as_float(e0.y);
    float4 v0 = *reinterpret_cast<const float4*>(Tcur + (size_t)e0.x*FP + lane*4);
    a0.x = fmaf(w0, v0.x, a0.x); a0.y = fmaf(w0, v0.y, a0.y);
    a0.z = fmaf(w0, v0.z, a0.z); a0.w = fmaf(w0, v0.w, a0.w);
  }
  size_t i = (size_t)n*FP + lane*4;
  float4 p = *reinterpret_cast<const float4*>(Tprev + i);
  float4 o;
  o.x = A*(a0.x + a1.x) - B*p.x;
  o.y = A*(a0.y + a1.y) - B*p.y;
  o.z = A*(a0.z + a1.z) - B*p.z;
  o.w = A*(a0.w + a1.w) - B*p.w;
  *reinterpret_cast<float4*>(Tnew + i) = o;
}

// U[t] = sum_k c[t][k] T_k   (t=0..5; c[0][k]=delta_k0 so U[0]=x padded)
struct Coefs { float c[TSNAPS][CHEB_D + 1]; };
__global__ __launch_bounds__(256) void k_combine(const float* __restrict__ T,
    float* __restrict__ U, Coefs cf){
  size_t i = ((size_t)blockIdx.x*256 + threadIdx.x) * 4;
  if (i >= NFP) return;
  float4 acc[TSNAPS];
  #pragma unroll
  for (int t = 0; t < TSNAPS; ++t) acc[t] = make_float4(0,0,0,0);
  #pragma unroll
  for (int k = 0; k <= CHEB_D; ++k){
    float4 tv = *reinterpret_cast<const float4*>(T + (size_t)k*NFP + i);
    #pragma unroll
    for (int t = 0; t < TSNAPS; ++t){
      float c = cf.c[t][k];
      acc[t].x = fmaf(c, tv.x, acc[t].x);
      acc[t].y = fmaf(c, tv.y, acc[t].y);
      acc[t].z = fmaf(c, tv.z, acc[t].z);
      acc[t].w = fmaf(c, tv.w, acc[t].w);
    }
  }
  #pragma unroll
  for (int t = 0; t < TSNAPS; ++t)
    *reinterpret_cast<float4*>(U + (size_t)t*NFP + i) = acc[t];
}

// unweighted 1-hop neighbor sum, ALL 6 snapshots fused:
// per edge: one col load, one address base, 6 independent float4 gathers
__global__ __launch_bounds__(256) void k_khop6(const int* __restrict__ rp,
    const int* __restrict__ col, const float* __restrict__ xin, float* __restrict__ xout){
  int tid = blockIdx.x*256 + threadIdx.x;
  int lane = tid & 7;
  int n = tid >> 3;
  if (n >= NNODES) return;
  int beg = rp[n], end = rp[n+1];
  float4 acc[TSNAPS];
  #pragma unroll
  for (int t = 0; t < TSNAPS; ++t) acc[t] = make_float4(0,0,0,0);
  for (int e = beg; e < end; ++e){
    const float* base = xin + (size_t)col[e]*FP + lane*4;
    #pragma unroll
    for (int t = 0; t < TSNAPS; ++t){
      float4 v = *reinterpret_cast<const float4*>(base + (size_t)t*NFP);
      acc[t].x += v.x; acc[t].y += v.y; acc[t].z += v.z; acc[t].w += v.w;
    }
  }
  size_t i = (size_t)n*FP + lane*4;
  #pragma unroll
  for (int t = 0; t < TSNAPS; ++t)
    *reinterpret_cast<float4*>(xout + (size_t)t*NFP + i) = acc[t];
}

// power-sum moments: g[t,s,kk,m,f] += sum_n hk[t,n,f]^((m+1)(s+1))
#define MCHUNK 512
__global__ __launch_bounds__(256) void k_moments(const float* __restrict__ hk,
    float* __restrict__ g, int kk){
  int t   = blockIdx.y;
  int f   = threadIdx.x & 31;
  int sub = threadIdx.x >> 5;            // 0..7
  const float* ht = hk + (size_t)t*NFP;
  int n0 = blockIdx.x*MCHUNK;
  int n1 = n0 + MCHUNK; if (n1 > NNODES) n1 = NNODES;
  float s1=0,s2=0,s3=0,s4=0,s6=0,s8=0,s9=0,s12=0;
  if (f < NFEATS){
    for (int n = n0 + sub; n < n1; n += 8){
      float h = ht[(size_t)n*FP + f];
      float p2=h*h, p3=p2*h, p4=p2*p2, p6=p3*p3, p8=p4*p4, p9=p8*h, p12=p6*p6;
      s1+=h; s2+=p2; s3+=p3; s4+=p4; s6+=p6; s8+=p8; s9+=p9; s12+=p12;
    }
  }
  __shared__ float red[8][256];
  red[0][threadIdx.x]=s1; red[1][threadIdx.x]=s2; red[2][threadIdx.x]=s3; red[3][threadIdx.x]=s4;
  red[4][threadIdx.x]=s6; red[5][threadIdx.x]=s8; red[6][threadIdx.x]=s9; red[7][threadIdx.x]=s12;
  __syncthreads();
  if (sub == 0 && f < NFEATS){
    float tot[8];
    #pragma unroll
    for (int p=0;p<8;p++){
      float s=0;
      #pragma unroll
      for (int q=0;q<8;q++) s += red[p][f + 32*q];
      tot[p]=s;
    }
    const int map[3][4] = {{0,1,2,3},{1,3,4,5},{2,4,6,7}};
    #pragma unroll
    for (int s=0;s<3;s++)
      #pragma unroll
      for (int m=0;m<4;m++){
        int idx = ((((t*3+s)*4+kk)*4+m)*NFEATS) + f;
        atomicAdd(&g[idx], tot[map[s][m]]);
      }
  }
}

// one row per block, float4 nontemporal streaming, LDS reduce
__global__ __launch_bounds__(256) void k_matvec(const float* __restrict__ W,
    const float* __restrict__ vin, const float* __restrict__ bias,
    float* __restrict__ vout, int cols, int do_relu){
  int row = blockIdx.x;
  const float* Wr = W + (size_t)row*cols;
  float acc = 0.f;
  for (int j = threadIdx.x*4; j < cols; j += 1024){
    vf4 wv = __builtin_nontemporal_load(reinterpret_cast<const vf4*>(Wr + j));
    float4 xv = *reinterpret_cast<const float4*>(vin + j);
    acc = fmaf(wv.x, xv.x, acc);
    acc = fmaf(wv.y, xv.y, acc);
    acc = fmaf(wv.z, xv.z, acc);
    acc = fmaf(wv.w, xv.w, acc);
  }
  __shared__ float red[256];
  red[threadIdx.x] = acc;
  __syncthreads();
  for (int off = 128; off > 0; off >>= 1){
    if (threadIdx.x < off) red[threadIdx.x] += red[threadIdx.x + off];
    __syncthreads();
  }
  if (threadIdx.x == 0){
    float r = red[0] + bias[row];
    vout[row] = do_relu ? fmaxf(r, 0.f) : r;
  }
}

// ---------------------------------------------------------------- host

// modified Bessel I_k(a) by series, double precision
static double bessel_i(int k, double a){
  double half = 0.5 * a;
  double t = 1.0;
  for (int q = 1; q <= k; ++q) t *= half / (double)q;   // half^k / k!
  double sum = t;
  for (int m = 1; m < 80; ++m){
    t *= half * half / ((double)m * (double)(m + k));
    sum += t;
    if (t < sum * 1e-18) break;
  }
  return sum;
}

extern "C" void kernel_launch(void* const* d_in, const int* in_sizes, int n_in,
                              void* d_out, int out_size, void* d_ws, size_t ws_size,
                              hipStream_t stream) {
  const float* x    = (const float*)d_in[0];
  const int*   ei   = (const int*)  d_in[1];
  const int*   esrc = ei;
  const int*   edst = ei + NEDGES;
  const float* W1   = (const float*)d_in[2];
  const float* b1   = (const float*)d_in[3];
  const float* W2   = (const float*)d_in[4];
  const float* b2   = (const float*)d_in[5];
  const float* Wc   = (const float*)d_in[6];
  const float* bc   = (const float*)d_in[7];
  float* out = (float*)d_out;

  // workspace layout (256B-aligned slices)
  char* wp = (char*)d_ws;
  auto alloc = [&](size_t bytes)->void*{
    void* p = wp; wp += ((bytes + 255) / 256) * 256; return p;
  };
  int*   deg   = (int*)  alloc(NNODES * 4);
  int*   fillc = (int*)  alloc(NNODES * 4);
  float* g     = (float*)alloc(HIDDEN * 4);
  int*   rp    = (int*)  alloc((NNODES + 1) * 4);
  int*   col   = (int*)  alloc(NEDGES * 4);
  int2*  edge  = (int2*) alloc(NEDGES * 8);
  float* Tbuf  = (float*)alloc((CHEB_D + 1) * NFP * 4);   // Chebyshev basis vectors
  float* U     = (float*)alloc(TSNAPS * NFP * 4);         // snapshots t=0..5
  float* hkA   = (float*)alloc(TSNAPS * NFP * 4);
  float* hkB   = (float*)alloc(TSNAPS * NFP * 4);
  float* v1    = (float*)alloc(HIDDEN * 4);
  float* v2    = (float*)alloc(HIDDEN * 4);

  (void)hipMemsetAsync(deg,   0, NNODES * 4, stream);
  (void)hipMemsetAsync(fillc, 0, NNODES * 4, stream);
  (void)hipMemsetAsync(g,     0, HIDDEN * 4, stream);

  // CSR by dst + sym-normalized weights (pre-scaled by 1/SIGMA)
  k_hist<<<(NEDGES + 255)/256, 256, 0, stream>>>(edst, deg);
  k_scan<<<1, 1024, 0, stream>>>(deg, rp);
  k_fill<<<(NEDGES + 255)/256, 256, 0, stream>>>(esrc, edst, rp, deg, fillc, col, edge,
                                                 (float)(1.0 / SIGMA));

  // T0 = x padded to stride 32 (pad columns zero)
  k_pad<<<(NNODES*32 + 255)/256, 256, 0, stream>>>(x, Tbuf);

  // Chebyshev basis: T_k = T_k(P/SIGMA) x via 3-term recurrence (one SpMV each)
  const int nb8 = (NNODES*8 + 255)/256;   // 938
  for (int k = 1; k <= CHEB_D; ++k){
    const float* Tc = Tbuf + (size_t)(k-1)*NFP;
    const float* Tp = Tbuf + (size_t)((k >= 2) ? (k-2) : 0)*NFP;
    float*       Tn = Tbuf + (size_t)k*NFP;
    k_cheb<<<nb8, 256, 0, stream>>>(rp, edge, Tc, Tp, Tn,
                                    (k == 1) ? 1.f : 2.f, (k == 1) ? 0.f : 1.f);
  }

  // u[t] = e^{-t} [ I0(t*SIGMA) + 2 sum_k Ik(t*SIGMA) T_k(P/SIGMA) ] x
  Coefs cf{};
  cf.c[0][0] = 1.f;
  for (int t = 1; t < TSNAPS; ++t){
    double et = exp(-(double)t);
    for (int k = 0; k <= CHEB_D; ++k)
      cf.c[t][k] = (float)(et * (k ? 2.0 : 1.0) * bessel_i(k, (double)t * SIGMA));
  }
  k_combine<<<(int)((NFP/4 + 255)/256), 256, 0, stream>>>(Tbuf, U, cf);

  // k-hop sums (unweighted, cumulative), all 6 snapshots fused per hop + graph moments
  dim3 mg((NNODES + MCHUNK - 1)/MCHUNK, TSNAPS);
  const float* hin = U;
  float* hop[2] = { hkA, hkB };
  for (int k = 0; k < 4; ++k){
    float* ho = hop[k & 1];
    k_khop6  <<<nb8, 256, 0, stream>>>(rp, col, hin, ho);
    k_moments<<<mg, 256, 0, stream>>>(ho, g, k);
    hin = ho;
  }

  // MLP head: v=g -> relu(W1 v+b1) -> relu(W2 .+b2) -> Wc .+bc
  k_matvec<<<HIDDEN, 256, 0, stream>>>(W1, g,  b1, v1,  HIDDEN, 1);
  k_matvec<<<HIDDEN, 256, 0, stream>>>(W2, v1, b2, v2,  HIDDEN, 1);
  k_matvec<<<NOUT,   256, 0, stream>>>(Wc, v2, bc, out, HIDDEN, 0);
}